// Round 1
// baseline (1079.796 us; speedup 1.0000x reference)
//
#include <hip/hip_runtime.h>
#include <cstdint>
#include <cstddef>

#define NEG_SLOPE 0.2f

// =====================================================================
// GEMM: C[M x 2*dout] = A[M x 128] @ [Wl | Wr] + [bl | br]
// BM=64, BN=64, BK=32, 256 threads, 4x4 register tile per thread.
// A tile stored transposed in LDS (As[k][m], pad +4) so both operand
// reads are aligned float4 (ds_read_b128).
// =====================================================================
template<int BM, int BN, int BK>
__global__ __launch_bounds__(256) void gemm_xlxr(
    const float* __restrict__ A, int lda, int M,
    const float* __restrict__ Wl, const float* __restrict__ Wr,
    const float* __restrict__ bl, const float* __restrict__ br,
    int dout, float* __restrict__ C)
{
    constexpr int PAD = 4;
    __shared__ float As[BK * (BM + PAD)];
    __shared__ float Bs[BK * BN];
    const int Ncols = 2 * dout;
    const int t = threadIdx.x;
    const int m0 = blockIdx.x * BM;
    const int n0 = blockIdx.y * BN;
    const int tm = (t / 16) * 4;
    const int tn = (t % 16) * 4;
    float acc[4][4] = {};

    for (int k0 = 0; k0 < 128; k0 += BK) {
        // ---- load A tile (BM x BK), store transposed As[k][m]
#pragma unroll
        for (int i = 0; i < (BM * BK) / (256 * 4); ++i) {
            int chunk = t + i * 256;
            int m  = chunk >> 3;          // BK/4 = 8 float4-chunks per row
            int kc = (chunk & 7) * 4;
            int row = m0 + m;
            float4 av = make_float4(0.f, 0.f, 0.f, 0.f);
            if (row < M) av = *(const float4*)(A + (size_t)row * lda + k0 + kc);
            As[(kc + 0) * (BM + PAD) + m] = av.x;
            As[(kc + 1) * (BM + PAD) + m] = av.y;
            As[(kc + 2) * (BM + PAD) + m] = av.z;
            As[(kc + 3) * (BM + PAD) + m] = av.w;
        }
        // ---- load B tile (BK x BN) from [Wl | Wr]
#pragma unroll
        for (int i = 0; i < (BK * BN) / (256 * 4); ++i) {
            int chunk = t + i * 256;
            int k  = chunk >> 4;          // BN/4 = 16 float4-chunks per row
            int nc = (chunk & 15) * 4;
            int ng = n0 + nc;
            const float* sp = (ng < dout) ? (Wl + (size_t)(k0 + k) * dout + ng)
                                          : (Wr + (size_t)(k0 + k) * dout + (ng - dout));
            *(float4*)(Bs + k * BN + nc) = *(const float4*)sp;
        }
        __syncthreads();
#pragma unroll
        for (int k = 0; k < BK; ++k) {
            float4 a = *(const float4*)(As + k * (BM + PAD) + tm);
            float4 b = *(const float4*)(Bs + k * BN + tn);
            float av[4] = {a.x, a.y, a.z, a.w};
            float bv[4] = {b.x, b.y, b.z, b.w};
#pragma unroll
            for (int ii = 0; ii < 4; ++ii)
#pragma unroll
                for (int jj = 0; jj < 4; ++jj)
                    acc[ii][jj] = fmaf(av[ii], bv[jj], acc[ii][jj]);
        }
        __syncthreads();
    }
#pragma unroll
    for (int ii = 0; ii < 4; ++ii) {
        int row = m0 + tm + ii;
        if (row >= M) continue;
        float4 v;
        float* vv = (float*)&v;
#pragma unroll
        for (int jj = 0; jj < 4; ++jj) {
            int col = n0 + tn + jj;
            float bia = (col < dout) ? bl[col] : br[col - dout];
            vv[jj] = acc[ii][jj] + bia;
        }
        *(float4*)(C + (size_t)row * Ncols + n0 + tn) = v;
    }
}

// =====================================================================
// CSR build over dst
// =====================================================================
__global__ void count_kernel(const int* __restrict__ dst, int E, int* __restrict__ cnt)
{
    int e = blockIdx.x * blockDim.x + threadIdx.x;
    if (e < E) atomicAdd(&cnt[dst[e]], 1);
}

__global__ __launch_bounds__(1024) void scan_kernel(
    const int* __restrict__ cnt, int N, int E,
    int* __restrict__ rowptr, int* __restrict__ cursor)
{
    __shared__ int part[1024];
    const int t = threadIdx.x;
    const int per = (N + 1023) >> 10;
    const int lo = t * per;
    const int hi = min(lo + per, N);
    int s = 0;
    for (int i = lo; i < hi; ++i) s += cnt[i];
    part[t] = s;
    __syncthreads();
    for (int off = 1; off < 1024; off <<= 1) {
        int v = (t >= off) ? part[t - off] : 0;
        __syncthreads();
        part[t] += v;
        __syncthreads();
    }
    int base = part[t] - s;   // exclusive prefix
    for (int i = lo; i < hi; ++i) {
        rowptr[i] = base;
        cursor[i] = base;
        base += cnt[i];
    }
    if (t == 1023) rowptr[N] = E;
}

__global__ void scatter_kernel(const int* __restrict__ dst, int E,
                               int* __restrict__ cursor, int* __restrict__ elist)
{
    int e = blockIdx.x * blockDim.x + threadIdx.x;
    if (e < E) {
        int p = atomicAdd(&cursor[dst[e]], 1);
        elist[p] = e;
    }
}

// =====================================================================
// Edge logits: logit[e][h] = sum_c att[h][c]*leakyrelu(xl[s][h][c]+xr[d][h][c])
// xlr row layout: [xl (HC) | xr (HC)], row stride RS = 2*HC.
// One edge per (HC/2)-lane group, float2 per lane, shfl width-16 head reduce.
// Edges e >= E are self-loops (s = d = e - E).
// =====================================================================
template<int H>
__global__ void edge_logits(
    const float* __restrict__ xlr, const int* __restrict__ src, const int* __restrict__ dst,
    int E, int N, const float* __restrict__ att, float* __restrict__ logits)
{
    constexpr int HC  = 32 * H;
    constexpr int RS  = 2 * HC;
    constexpr int LPE = HC / 2;     // lanes per edge (float2 each)
    constexpr int EPW = 64 / LPE;   // edges per wave
    const int lane = threadIdx.x & 63;
    const int wid  = blockIdx.x * (blockDim.x >> 6) + (threadIdx.x >> 6);
    const int sub  = lane / LPE;
    const int q    = lane % LPE;
    const int Ep   = E + N;
    const int e    = wid * EPW + sub;
    if (e >= Ep) return;
    int s, d;
    if (e < E) { s = src[e]; d = dst[e]; } else { s = e - E; d = s; }
    const float2 u = *(const float2*)(xlr + (size_t)s * RS + 2 * q);
    const float2 v = *(const float2*)(xlr + (size_t)d * RS + HC + 2 * q);
    const float2 a = *(const float2*)(att + 2 * q);
    float sx = u.x + v.x, sy = u.y + v.y;
    sx = (sx > 0.f) ? sx : NEG_SLOPE * sx;
    sy = (sy > 0.f) ? sy : NEG_SLOPE * sy;
    float p = fmaf(a.x, sx, a.y * sy);
#pragma unroll
    for (int off = 8; off >= 1; off >>= 1)
        p += __shfl_xor(p, off, 16);
    if ((q & 15) == 0)
        logits[(size_t)e * H + (q >> 4)] = p;
}

// =====================================================================
// Fused per-dst softmax + aggregation + bias + ELU.
// One block per node. Groups of 32 lanes own one head for the max/denom
// reductions; all HC threads aggregate. CSR edges chunked via LDS.
// =====================================================================
template<int H>
__global__ void gat_aggregate(
    const float* __restrict__ xlr, const float* __restrict__ logits,
    const int* __restrict__ rowptr, const int* __restrict__ elist,
    const int* __restrict__ src, int E,
    const float* __restrict__ bias, float* __restrict__ hout, int hstride)
{
    constexpr int HC = 32 * H;
    constexpr int RS = 2 * HC;
    constexpr int CH = 128;
    __shared__ int   s_src[CH];
    __shared__ float s_log[CH * H];
    __shared__ float mxs[H], dens[H], wsl[H];
    const int i  = blockIdx.x;
    const int t  = threadIdx.x;
    const int g  = t >> 5;
    const int lc = t & 31;
    const int rs = rowptr[i];
    const int deg = rowptr[i + 1] - rs;

    // ---- pass 1: per-head max over incoming edges
    float mx = -3.4e38f;
    for (int base = 0; base < deg; base += CH) {
        int cnt = min(CH, deg - base);
        __syncthreads();
        if (t < cnt) {
            int e = elist[rs + base + t];
#pragma unroll
            for (int hh = 0; hh < H; ++hh)
                s_log[t * H + hh] = logits[(size_t)e * H + hh];
        }
        __syncthreads();
        if (g < H)
            for (int k = lc; k < cnt; k += 32)
                mx = fmaxf(mx, s_log[k * H + g]);
    }
#pragma unroll
    for (int off = 16; off >= 1; off >>= 1)
        mx = fmaxf(mx, __shfl_xor(mx, off, 32));
    if (g < H && lc == 0)
        mxs[g] = fmaxf(mx, logits[(size_t)(E + i) * H + g]);  // include self-loop
    __syncthreads();

    // ---- pass 2: exp-weights, denominator, weighted aggregation
    float den = 0.f, acc = 0.f;
    for (int base = 0; base < deg; base += CH) {
        int cnt = min(CH, deg - base);
        __syncthreads();
        if (t < cnt) {
            int e = elist[rs + base + t];
            s_src[t] = src[e];
#pragma unroll
            for (int hh = 0; hh < H; ++hh)
                s_log[t * H + hh] = logits[(size_t)e * H + hh];
        }
        __syncthreads();
        if (g < H)
            for (int k = lc; k < cnt; k += 32) {
                float w = expf(s_log[k * H + g] - mxs[g]);
                s_log[k * H + g] = w;
                den += w;
            }
        __syncthreads();
        if (t < HC) {
            float a = 0.f;
            for (int k = 0; k < cnt; ++k)
                a = fmaf(s_log[k * H + g], xlr[(size_t)s_src[k] * RS + t], a);
            acc += a;
        }
    }
#pragma unroll
    for (int off = 16; off >= 1; off >>= 1)
        den += __shfl_xor(den, off, 32);
    if (g < H && lc == 0) {
        float ws = expf(logits[(size_t)(E + i) * H + g] - mxs[g]);
        dens[g] = den + ws;
        wsl[g]  = ws;
    }
    __syncthreads();
    if (t < HC) {
        acc = fmaf(wsl[g], xlr[(size_t)i * RS + t], acc);   // self-loop term
        float v = acc / (dens[g] + 1e-16f) + bias[t];
        v = (v > 0.f) ? v : expm1f(v);                      // ELU
        hout[(size_t)i * hstride + t] = v;
    }
}

// =====================================================================
// Global mean pool (atomics) and MLP head
// =====================================================================
__global__ void pool_kernel(const float* __restrict__ h, int hstride,
                            const int* __restrict__ batch, int N,
                            float* __restrict__ pool, float* __restrict__ pcnt)
{
    int idx = blockIdx.x * blockDim.x + threadIdx.x;
    int n = idx >> 5, c = idx & 31;
    if (n >= N) return;
    int b = batch[n];
    atomicAdd(&pool[(size_t)b * 32 + c], h[(size_t)n * hstride + c]);
    if (c == 0) atomicAdd(&pcnt[b], 1.0f);
}

__global__ void head_kernel(const float* __restrict__ pool, const float* __restrict__ pcnt,
                            const float* __restrict__ meta,
                            const float* __restrict__ Wh1, const float* __restrict__ bh1,
                            const float* __restrict__ Wh2, const float* __restrict__ bh2,
                            float* __restrict__ out)
{
    const int b = blockIdx.x;
    const int t = threadIdx.x;
    __shared__ float z[44];
    if (t < 32)      z[t] = pool[(size_t)b * 32 + t] / fmaxf(pcnt[b], 1.0f);
    else if (t < 44) z[t] = meta[(size_t)b * 12 + (t - 32)];
    __syncthreads();
    float p = 0.f;
    if (t < 32) {
        float hj = bh1[t];
#pragma unroll
        for (int k = 0; k < 44; ++k)
            hj = fmaf(z[k], Wh1[k * 32 + t], hj);
        hj = fmaxf(hj, 0.f);
        p = hj * Wh2[t];
    }
#pragma unroll
    for (int off = 32; off >= 1; off >>= 1)
        p += __shfl_xor(p, off, 64);
    if (t == 0) out[b] = p + bh2[0];
}

// =====================================================================
extern "C" void kernel_launch(void* const* d_in, const int* in_sizes, int n_in,
                              void* d_out, int out_size, void* d_ws, size_t ws_size,
                              hipStream_t stream)
{
    const float* x     = (const float*)d_in[0];
    const int*   ei    = (const int*)d_in[1];
    const int*   batch = (const int*)d_in[2];
    const float* meta  = (const float*)d_in[3];
    const float* Wl[3]  = {(const float*)d_in[4],  (const float*)d_in[10], (const float*)d_in[16]};
    const float* bl[3]  = {(const float*)d_in[5],  (const float*)d_in[11], (const float*)d_in[17]};
    const float* Wr[3]  = {(const float*)d_in[6],  (const float*)d_in[12], (const float*)d_in[18]};
    const float* br[3]  = {(const float*)d_in[7],  (const float*)d_in[13], (const float*)d_in[19]};
    const float* att[3] = {(const float*)d_in[8],  (const float*)d_in[14], (const float*)d_in[20]};
    const float* bb[3]  = {(const float*)d_in[9],  (const float*)d_in[15], (const float*)d_in[21]};
    const float* Wh1 = (const float*)d_in[22];
    const float* bh1 = (const float*)d_in[23];
    const float* Wh2 = (const float*)d_in[24];
    const float* bh2 = (const float*)d_in[25];
    float* out = (float*)d_out;

    const int N  = in_sizes[0] / 128;
    const int E  = in_sizes[1] / 2;
    const int B  = in_sizes[3] / 12;
    const int Ep = E + N;

    char* wsp = (char*)d_ws;
    size_t off_ = 0;
    auto alloc = [&](size_t bytes) {
        char* p = wsp + off_;
        off_ = (off_ + bytes + 255) & ~(size_t)255;
        return p;
    };
    float* xlr    = (float*)alloc((size_t)N * 256 * 4);   // [xl | xr], stride 2*HC
    float* hbuf   = (float*)alloc((size_t)N * 128 * 4);   // layer output (ELU'd)
    float* logits = (float*)alloc((size_t)Ep * 4 * 4);    // E' x H (H<=4)
    int*   cnt    = (int*)alloc((size_t)N * 4);
    int*   rowptr = (int*)alloc((size_t)(N + 1) * 4);
    int*   cursor = (int*)alloc((size_t)N * 4);
    int*   elist  = (int*)alloc((size_t)E * 4);
    float* pool   = (float*)alloc((size_t)B * 32 * 4);
    float* pcnt   = (float*)alloc((size_t)B * 4);

    const int* srcI = ei;
    const int* dstI = ei + E;

    // ---- CSR over dst (real edges only; self-loops handled implicitly)
    hipMemsetAsync(cnt, 0, (size_t)N * 4, stream);
    count_kernel<<<(E + 255) / 256, 256, 0, stream>>>(dstI, E, cnt);
    scan_kernel<<<1, 1024, 0, stream>>>(cnt, N, E, rowptr, cursor);
    scatter_kernel<<<(E + 255) / 256, 256, 0, stream>>>(dstI, E, cursor, elist);

    // ---- layer 0 (din=128, H=4, C=32, concat)
    {
        dim3 g((N + 63) / 64, 4);
        gemm_xlxr<64, 64, 32><<<g, 256, 0, stream>>>(x, 128, N, Wl[0], Wr[0], bl[0], br[0], 128, xlr);
        edge_logits<4><<<(Ep + 3) / 4, 256, 0, stream>>>(xlr, srcI, dstI, E, N, att[0], logits);
        gat_aggregate<4><<<N, 128, 0, stream>>>(xlr, logits, rowptr, elist, srcI, E, bb[0], hbuf, 128);
    }
    // ---- layer 1
    {
        dim3 g((N + 63) / 64, 4);
        gemm_xlxr<64, 64, 32><<<g, 256, 0, stream>>>(hbuf, 128, N, Wl[1], Wr[1], bl[1], br[1], 128, xlr);
        edge_logits<4><<<(Ep + 3) / 4, 256, 0, stream>>>(xlr, srcI, dstI, E, N, att[1], logits);
        gat_aggregate<4><<<N, 128, 0, stream>>>(xlr, logits, rowptr, elist, srcI, E, bb[1], hbuf, 128);
    }
    // ---- layer 2 (H=1, concat=False -> mean over 1 head = identity)
    {
        dim3 g((N + 63) / 64, 1);
        gemm_xlxr<64, 64, 32><<<g, 256, 0, stream>>>(hbuf, 128, N, Wl[2], Wr[2], bl[2], br[2], 32, xlr);
        int waves = (Ep + 3) / 4;   // 4 edges per wave for H=1
        edge_logits<1><<<(waves + 3) / 4, 256, 0, stream>>>(xlr, srcI, dstI, E, N, att[2], logits);
        gat_aggregate<1><<<N, 64, 0, stream>>>(xlr, logits, rowptr, elist, srcI, E, bb[2], hbuf, 32);
    }
    // ---- global mean pool + head
    hipMemsetAsync(pool, 0, (size_t)B * 32 * 4, stream);
    hipMemsetAsync(pcnt, 0, (size_t)B * 4, stream);
    pool_kernel<<<((N * 32) + 255) / 256, 256, 0, stream>>>(hbuf, 32, batch, N, pool, pcnt);
    head_kernel<<<B, 64, 0, stream>>>(pool, pcnt, meta, Wh1, bh1, Wh2, bh2, out);
}

// Round 2
// 825.753 us; speedup vs baseline: 1.3076x; 1.3076x over previous
//
#include <hip/hip_runtime.h>
#include <cstdint>
#include <cstddef>

#define NEG_SLOPE 0.2f

// =====================================================================
// GEMM: [XL | XR][M x dout each] = A[M x 128] @ [Wl | Wr] + [bl | br]
// BM=64, BN=64, BK=32, 256 threads, 4x4 register tile per thread.
// A tile stored transposed in LDS (As[k][m], pad +4) so both operand
// reads are aligned float4 (ds_read_b128). Outputs split into separate
// XL / XR tables for the fused attention kernel.
// =====================================================================
template<int BM, int BN, int BK>
__global__ __launch_bounds__(256) void gemm_xlxr(
    const float* __restrict__ A, int lda, int M,
    const float* __restrict__ Wl, const float* __restrict__ Wr,
    const float* __restrict__ bl, const float* __restrict__ br,
    int dout, float* __restrict__ XL, float* __restrict__ XR)
{
    constexpr int PAD = 4;
    __shared__ float As[BK * (BM + PAD)];
    __shared__ float Bs[BK * BN];
    const int t = threadIdx.x;
    const int m0 = blockIdx.x * BM;
    const int n0 = blockIdx.y * BN;
    const int tm = (t / 16) * 4;
    const int tn = (t % 16) * 4;
    float acc[4][4] = {};

    for (int k0 = 0; k0 < 128; k0 += BK) {
        // ---- load A tile (BM x BK), store transposed As[k][m]
#pragma unroll
        for (int i = 0; i < (BM * BK) / (256 * 4); ++i) {
            int chunk = t + i * 256;
            int m  = chunk >> 3;          // BK/4 = 8 float4-chunks per row
            int kc = (chunk & 7) * 4;
            int row = m0 + m;
            float4 av = make_float4(0.f, 0.f, 0.f, 0.f);
            if (row < M) av = *(const float4*)(A + (size_t)row * lda + k0 + kc);
            As[(kc + 0) * (BM + PAD) + m] = av.x;
            As[(kc + 1) * (BM + PAD) + m] = av.y;
            As[(kc + 2) * (BM + PAD) + m] = av.z;
            As[(kc + 3) * (BM + PAD) + m] = av.w;
        }
        // ---- load B tile (BK x BN) from [Wl | Wr]
#pragma unroll
        for (int i = 0; i < (BK * BN) / (256 * 4); ++i) {
            int chunk = t + i * 256;
            int k  = chunk >> 4;          // BN/4 = 16 float4-chunks per row
            int nc = (chunk & 15) * 4;
            int ng = n0 + nc;
            const float* sp = (ng < dout) ? (Wl + (size_t)(k0 + k) * dout + ng)
                                          : (Wr + (size_t)(k0 + k) * dout + (ng - dout));
            *(float4*)(Bs + k * BN + nc) = *(const float4*)sp;
        }
        __syncthreads();
#pragma unroll
        for (int k = 0; k < BK; ++k) {
            float4 a = *(const float4*)(As + k * (BM + PAD) + tm);
            float4 b = *(const float4*)(Bs + k * BN + tn);
            float av[4] = {a.x, a.y, a.z, a.w};
            float bv[4] = {b.x, b.y, b.z, b.w};
#pragma unroll
            for (int ii = 0; ii < 4; ++ii)
#pragma unroll
                for (int jj = 0; jj < 4; ++jj)
                    acc[ii][jj] = fmaf(av[ii], bv[jj], acc[ii][jj]);
        }
        __syncthreads();
    }
#pragma unroll
    for (int ii = 0; ii < 4; ++ii) {
        int row = m0 + tm + ii;
        if (row >= M) continue;
        int col = n0 + tn;                 // 4-col group lies in one half (dout % 4 == 0)
        const float* bp = (col < dout) ? (bl + col) : (br + (col - dout));
        float4 v;
        float* vv = (float*)&v;
#pragma unroll
        for (int jj = 0; jj < 4; ++jj) vv[jj] = acc[ii][jj] + bp[jj];
        float* outp = (col < dout) ? (XL + (size_t)row * dout + col)
                                   : (XR + (size_t)row * dout + (col - dout));
        *(float4*)outp = v;
    }
}

// =====================================================================
// CSR build over dst (csr_src[p] holds src of each edge, grouped by dst)
// =====================================================================
__global__ void count_kernel(const int* __restrict__ dst, int E, int* __restrict__ cnt)
{
    int e = blockIdx.x * blockDim.x + threadIdx.x;
    if (e < E) atomicAdd(&cnt[dst[e]], 1);
}

__global__ __launch_bounds__(1024) void scan_kernel(
    const int* __restrict__ cnt, int N, int E,
    int* __restrict__ rowptr, int* __restrict__ cursor)
{
    __shared__ int part[1024];
    const int t = threadIdx.x;
    const int per = (N + 1023) >> 10;
    const int lo = t * per;
    const int hi = min(lo + per, N);
    int s = 0;
    for (int i = lo; i < hi; ++i) s += cnt[i];
    part[t] = s;
    __syncthreads();
    for (int off = 1; off < 1024; off <<= 1) {
        int v = (t >= off) ? part[t - off] : 0;
        __syncthreads();
        part[t] += v;
        __syncthreads();
    }
    int base = part[t] - s;   // exclusive prefix
    for (int i = lo; i < hi; ++i) {
        rowptr[i] = base;
        cursor[i] = base;
        base += cnt[i];
    }
    if (t == 1023) rowptr[N] = E;
}

__global__ void scatter_kernel(const int* __restrict__ src, const int* __restrict__ dst,
                               int E, int* __restrict__ cursor, int* __restrict__ csr_src)
{
    int e = blockIdx.x * blockDim.x + threadIdx.x;
    if (e < E) {
        int p = atomicAdd(&cursor[dst[e]], 1);
        csr_src[p] = src[e];
    }
}

// =====================================================================
// Fused GATv2 edge phase: per-dst block computes logits on the fly
// (xr[dst] held in registers), online-softmax (running m, l, acc), and
// the weighted aggregation — each xl[src] row is gathered ONCE and used
// for both the logit and the accumulation. Epilogue: +bias, ELU.
// EPI = edges per iteration (2 for H=1 so a full wave is used; slot
// states merged at the end via softmax-state combine).
// =====================================================================
template<int H, int EPI>
__global__ __launch_bounds__(32 * H * EPI) void gat_fused(
    const float* __restrict__ xl, const float* __restrict__ xr,
    const int* __restrict__ rowptr, const int* __restrict__ csr_src,
    const float* __restrict__ att, const float* __restrict__ bias,
    float* __restrict__ hout, int hstride)
{
    constexpr int HC  = 32 * H;
    constexpr int BLK = HC * EPI;
    __shared__ int s_src[BLK];
    const int i    = blockIdx.x;
    const int t    = threadIdx.x;
    const int f    = t % HC;       // feature index (head g = f>>5, channel f&31)
    const int slot = t / HC;       // edge slot
    const int rs   = rowptr[i];
    const int deg  = rowptr[i + 1] - rs;

    const float xri = xr[(size_t)i * HC + f];
    const float af  = att[f];

    float m = -__builtin_inff(), l = 0.f, acc = 0.f;

    // ---- self-loop (src = dst = i), processed by slot 0 only
    if (slot == 0) {
        float v  = xl[(size_t)i * HC + f];
        float su = v + xri;
        su = (su > 0.f) ? su : NEG_SLOPE * su;
        float p = af * su;
#pragma unroll
        for (int off = 16; off >= 1; off >>= 1) p += __shfl_xor(p, off, 32);
        m = p; l = 1.f; acc = v;
    }

    // ---- incoming edges via CSR, online softmax
    for (int base = 0; base < deg; base += BLK) {
        int cnt = min(BLK, deg - base);
        __syncthreads();
        if (t < cnt) s_src[t] = csr_src[rs + base + t];
        __syncthreads();
        for (int k = slot; k < cnt; k += EPI) {
            int s    = s_src[k];
            float v  = xl[(size_t)s * HC + f];
            float su = v + xri;
            su = (su > 0.f) ? su : NEG_SLOPE * su;
            float p = af * su;
#pragma unroll
            for (int off = 16; off >= 1; off >>= 1) p += __shfl_xor(p, off, 32);
            float mn = fmaxf(m, p);
            float sc = __expf(m - mn);
            float w  = __expf(p - mn);
            l   = fmaf(l, sc, w);
            acc = fmaf(acc, sc, w * v);
            m = mn;
        }
    }

    // ---- merge edge slots (softmax-state combine across lane bit 5)
    if (EPI == 2) {
        float mo = __shfl_xor(m, 32, 64);
        float lo = __shfl_xor(l, 32, 64);
        float ao = __shfl_xor(acc, 32, 64);
        float mm = fmaxf(m, mo);
        float s0 = __expf(m - mm);
        float s1 = __expf(mo - mm);
        l   = l * s0 + lo * s1;
        acc = acc * s0 + ao * s1;
    }

    if (t < HC) {
        float v = acc / (l + 1e-16f) + bias[f];
        v = (v > 0.f) ? v : expm1f(v);     // ELU
        hout[(size_t)i * hstride + f] = v;
    }
}

// =====================================================================
// Global mean pool (atomics) and MLP head
// =====================================================================
__global__ void pool_kernel(const float* __restrict__ h, int hstride,
                            const int* __restrict__ batch, int N,
                            float* __restrict__ pool, float* __restrict__ pcnt)
{
    int idx = blockIdx.x * blockDim.x + threadIdx.x;
    int n = idx >> 5, c = idx & 31;
    if (n >= N) return;
    int b = batch[n];
    atomicAdd(&pool[(size_t)b * 32 + c], h[(size_t)n * hstride + c]);
    if (c == 0) atomicAdd(&pcnt[b], 1.0f);
}

__global__ void head_kernel(const float* __restrict__ pool, const float* __restrict__ pcnt,
                            const float* __restrict__ meta,
                            const float* __restrict__ Wh1, const float* __restrict__ bh1,
                            const float* __restrict__ Wh2, const float* __restrict__ bh2,
                            float* __restrict__ out)
{
    const int b = blockIdx.x;
    const int t = threadIdx.x;
    __shared__ float z[44];
    if (t < 32)      z[t] = pool[(size_t)b * 32 + t] / fmaxf(pcnt[b], 1.0f);
    else if (t < 44) z[t] = meta[(size_t)b * 12 + (t - 32)];
    __syncthreads();
    float p = 0.f;
    if (t < 32) {
        float hj = bh1[t];
#pragma unroll
        for (int k = 0; k < 44; ++k)
            hj = fmaf(z[k], Wh1[k * 32 + t], hj);
        hj = fmaxf(hj, 0.f);
        p = hj * Wh2[t];
    }
#pragma unroll
    for (int off = 32; off >= 1; off >>= 1)
        p += __shfl_xor(p, off, 64);
    if (t == 0) out[b] = p + bh2[0];
}

// =====================================================================
extern "C" void kernel_launch(void* const* d_in, const int* in_sizes, int n_in,
                              void* d_out, int out_size, void* d_ws, size_t ws_size,
                              hipStream_t stream)
{
    const float* x     = (const float*)d_in[0];
    const int*   ei    = (const int*)d_in[1];
    const int*   batch = (const int*)d_in[2];
    const float* meta  = (const float*)d_in[3];
    const float* Wl[3]  = {(const float*)d_in[4],  (const float*)d_in[10], (const float*)d_in[16]};
    const float* bl[3]  = {(const float*)d_in[5],  (const float*)d_in[11], (const float*)d_in[17]};
    const float* Wr[3]  = {(const float*)d_in[6],  (const float*)d_in[12], (const float*)d_in[18]};
    const float* br[3]  = {(const float*)d_in[7],  (const float*)d_in[13], (const float*)d_in[19]};
    const float* att[3] = {(const float*)d_in[8],  (const float*)d_in[14], (const float*)d_in[20]};
    const float* bb[3]  = {(const float*)d_in[9],  (const float*)d_in[15], (const float*)d_in[21]};
    const float* Wh1 = (const float*)d_in[22];
    const float* bh1 = (const float*)d_in[23];
    const float* Wh2 = (const float*)d_in[24];
    const float* bh2 = (const float*)d_in[25];
    float* out = (float*)d_out;

    const int N  = in_sizes[0] / 128;
    const int E  = in_sizes[1] / 2;
    const int B  = in_sizes[3] / 12;

    char* wsp = (char*)d_ws;
    size_t off_ = 0;
    auto alloc = [&](size_t bytes) {
        char* p = wsp + off_;
        off_ = (off_ + bytes + 255) & ~(size_t)255;
        return p;
    };
    float* xlbuf   = (float*)alloc((size_t)N * 128 * 4);  // xl table (HC <= 128)
    float* xrbuf   = (float*)alloc((size_t)N * 128 * 4);  // xr table
    float* hbuf    = (float*)alloc((size_t)N * 128 * 4);  // layer output (ELU'd)
    int*   cnt     = (int*)alloc((size_t)N * 4);
    int*   rowptr  = (int*)alloc((size_t)(N + 1) * 4);
    int*   cursor  = (int*)alloc((size_t)N * 4);
    int*   csr_src = (int*)alloc((size_t)E * 4);
    float* pool    = (float*)alloc((size_t)B * 32 * 4);
    float* pcnt    = (float*)alloc((size_t)B * 4);

    const int* srcI = ei;
    const int* dstI = ei + E;

    // ---- CSR over dst (real edges; self-loops handled inside gat_fused)
    hipMemsetAsync(cnt, 0, (size_t)N * 4, stream);
    count_kernel<<<(E + 255) / 256, 256, 0, stream>>>(dstI, E, cnt);
    scan_kernel<<<1, 1024, 0, stream>>>(cnt, N, E, rowptr, cursor);
    scatter_kernel<<<(E + 255) / 256, 256, 0, stream>>>(srcI, dstI, E, cursor, csr_src);

    // ---- layer 0 (din=128, H=4, C=32, concat)
    {
        dim3 g((N + 63) / 64, 4);
        gemm_xlxr<64, 64, 32><<<g, 256, 0, stream>>>(x, 128, N, Wl[0], Wr[0], bl[0], br[0], 128, xlbuf, xrbuf);
        gat_fused<4, 1><<<N, 128, 0, stream>>>(xlbuf, xrbuf, rowptr, csr_src, att[0], bb[0], hbuf, 128);
    }
    // ---- layer 1
    {
        dim3 g((N + 63) / 64, 4);
        gemm_xlxr<64, 64, 32><<<g, 256, 0, stream>>>(hbuf, 128, N, Wl[1], Wr[1], bl[1], br[1], 128, xlbuf, xrbuf);
        gat_fused<4, 1><<<N, 128, 0, stream>>>(xlbuf, xrbuf, rowptr, csr_src, att[1], bb[1], hbuf, 128);
    }
    // ---- layer 2 (H=1, concat=False -> mean over 1 head = identity)
    {
        dim3 g((N + 63) / 64, 1);
        gemm_xlxr<64, 64, 32><<<g, 256, 0, stream>>>(hbuf, 128, N, Wl[2], Wr[2], bl[2], br[2], 32, xlbuf, xrbuf);
        gat_fused<1, 2><<<N, 64, 0, stream>>>(xlbuf, xrbuf, rowptr, csr_src, att[2], bb[2], hbuf, 32);
    }
    // ---- global mean pool + head
    hipMemsetAsync(pool, 0, (size_t)B * 32 * 4, stream);
    hipMemsetAsync(pcnt, 0, (size_t)B * 4, stream);
    pool_kernel<<<((N * 32) + 255) / 256, 256, 0, stream>>>(hbuf, 32, batch, N, pool, pcnt);
    head_kernel<<<B, 64, 0, stream>>>(pool, pcnt, meta, Wh1, bh1, Wh2, bh2, out);
}

// Round 3
// 665.204 us; speedup vs baseline: 1.6233x; 1.2414x over previous
//
#include <hip/hip_runtime.h>
#include <cstdint>
#include <cstddef>

#define NEG_SLOPE 0.2f

// =====================================================================
// GEMM: [XL | XR][M x dout each] = A[M x 128] @ [Wl | Wr] + [bl | br]
// BM=64, BN=64, BK=32, 256 threads, 4x4 register tile per thread.
// =====================================================================
template<int BM, int BN, int BK>
__global__ __launch_bounds__(256) void gemm_xlxr(
    const float* __restrict__ A, int lda, int M,
    const float* __restrict__ Wl, const float* __restrict__ Wr,
    const float* __restrict__ bl, const float* __restrict__ br,
    int dout, float* __restrict__ XL, float* __restrict__ XR)
{
    constexpr int PAD = 4;
    __shared__ float As[BK * (BM + PAD)];
    __shared__ float Bs[BK * BN];
    const int t = threadIdx.x;
    const int m0 = blockIdx.x * BM;
    const int n0 = blockIdx.y * BN;
    const int tm = (t / 16) * 4;
    const int tn = (t % 16) * 4;
    float acc[4][4] = {};

    for (int k0 = 0; k0 < 128; k0 += BK) {
#pragma unroll
        for (int i = 0; i < (BM * BK) / (256 * 4); ++i) {
            int chunk = t + i * 256;
            int m  = chunk >> 3;
            int kc = (chunk & 7) * 4;
            int row = m0 + m;
            float4 av = make_float4(0.f, 0.f, 0.f, 0.f);
            if (row < M) av = *(const float4*)(A + (size_t)row * lda + k0 + kc);
            As[(kc + 0) * (BM + PAD) + m] = av.x;
            As[(kc + 1) * (BM + PAD) + m] = av.y;
            As[(kc + 2) * (BM + PAD) + m] = av.z;
            As[(kc + 3) * (BM + PAD) + m] = av.w;
        }
#pragma unroll
        for (int i = 0; i < (BK * BN) / (256 * 4); ++i) {
            int chunk = t + i * 256;
            int k  = chunk >> 4;
            int nc = (chunk & 15) * 4;
            int ng = n0 + nc;
            const float* sp = (ng < dout) ? (Wl + (size_t)(k0 + k) * dout + ng)
                                          : (Wr + (size_t)(k0 + k) * dout + (ng - dout));
            *(float4*)(Bs + k * BN + nc) = *(const float4*)sp;
        }
        __syncthreads();
#pragma unroll
        for (int k = 0; k < BK; ++k) {
            float4 a = *(const float4*)(As + k * (BM + PAD) + tm);
            float4 b = *(const float4*)(Bs + k * BN + tn);
            float av[4] = {a.x, a.y, a.z, a.w};
            float bv[4] = {b.x, b.y, b.z, b.w};
#pragma unroll
            for (int ii = 0; ii < 4; ++ii)
#pragma unroll
                for (int jj = 0; jj < 4; ++jj)
                    acc[ii][jj] = fmaf(av[ii], bv[jj], acc[ii][jj]);
        }
        __syncthreads();
    }
#pragma unroll
    for (int ii = 0; ii < 4; ++ii) {
        int row = m0 + tm + ii;
        if (row >= M) continue;
        int col = n0 + tn;                 // 4-col group lies in one half (dout % 4 == 0)
        const float* bp = (col < dout) ? (bl + col) : (br + (col - dout));
        float4 v;
        float* vv = (float*)&v;
#pragma unroll
        for (int jj = 0; jj < 4; ++jj) vv[jj] = acc[ii][jj] + bp[jj];
        float* outp = (col < dout) ? (XL + (size_t)row * dout + col)
                                   : (XR + (size_t)row * dout + (col - dout));
        *(float4*)outp = v;
    }
}

// =====================================================================
// CSR build over dst (csr_src[p] holds src of each edge, grouped by dst)
// =====================================================================
__global__ void count_kernel(const int* __restrict__ dst, int E, int* __restrict__ cnt)
{
    int e = blockIdx.x * blockDim.x + threadIdx.x;
    if (e < E) atomicAdd(&cnt[dst[e]], 1);
}

__global__ __launch_bounds__(1024) void scan_kernel(
    const int* __restrict__ cnt, int N, int E,
    int* __restrict__ rowptr, int* __restrict__ cursor)
{
    __shared__ int part[1024];
    const int t = threadIdx.x;
    const int per = (N + 1023) >> 10;
    const int lo = t * per;
    const int hi = min(lo + per, N);
    int s = 0;
    for (int i = lo; i < hi; ++i) s += cnt[i];
    part[t] = s;
    __syncthreads();
    for (int off = 1; off < 1024; off <<= 1) {
        int v = (t >= off) ? part[t - off] : 0;
        __syncthreads();
        part[t] += v;
        __syncthreads();
    }
    int base = part[t] - s;   // exclusive prefix
    for (int i = lo; i < hi; ++i) {
        rowptr[i] = base;
        cursor[i] = base;
        base += cnt[i];
    }
    if (t == 1023) rowptr[N] = E;
}

__global__ void scatter_kernel(const int* __restrict__ src, const int* __restrict__ dst,
                               int E, int* __restrict__ cursor, int* __restrict__ csr_src)
{
    int e = blockIdx.x * blockDim.x + threadIdx.x;
    if (e < E) {
        int p = atomicAdd(&cursor[dst[e]], 1);
        csr_src[p] = src[e];
    }
}

// =====================================================================
// Fused GATv2 edge phase, float4-per-lane:
//   LPE = HC/4 lanes per edge (H=4: 32, H=1: 8); EPW = 64/LPE edge slots
//   per wave (2 / 8). One wave per dst node. Each lane holds 4 channels;
//   per-head logit reduce = 3-step shfl_xor over the 8-lane head group.
//   Online softmax (running m, l, float4 acc) per slot; slots merged at
//   the end via softmax-state combine over xor masks LPE..32.
//   m init = -3e38 (finite!) so empty-slot merges don't produce NaN.
// =====================================================================
template<int H>
__global__ __launch_bounds__(64) void gat_fused(
    const float* __restrict__ xl, const float* __restrict__ xr,
    const int* __restrict__ rowptr, const int* __restrict__ csr_src,
    const float* __restrict__ att, const float* __restrict__ bias,
    float* __restrict__ hout, int hstride)
{
    constexpr int HC  = 32 * H;
    constexpr int LPE = HC / 4;      // lanes per edge
    constexpr int EPW = 64 / LPE;    // edge slots per wave
    __shared__ int s_src[64];
    const int i    = blockIdx.x;
    const int t    = threadIdx.x;
    const int q    = t % LPE;        // lane within edge group
    const int slot = t / LPE;
    const int rs   = rowptr[i];
    const int deg  = rowptr[i + 1] - rs;

    const float4 xri = *(const float4*)(xr + (size_t)i * HC + 4 * q);
    const float4 af  = *(const float4*)(att + 4 * q);

    float m = -3.0e38f, l = 0.f;
    float4 acc = make_float4(0.f, 0.f, 0.f, 0.f);

    auto edge_logit = [&](const float4& v) -> float {
        float sx = v.x + xri.x, sy = v.y + xri.y, sz = v.z + xri.z, sw = v.w + xri.w;
        sx = (sx > 0.f) ? sx : NEG_SLOPE * sx;
        sy = (sy > 0.f) ? sy : NEG_SLOPE * sy;
        sz = (sz > 0.f) ? sz : NEG_SLOPE * sz;
        sw = (sw > 0.f) ? sw : NEG_SLOPE * sw;
        float p = af.x * sx;
        p = fmaf(af.y, sy, p);
        p = fmaf(af.z, sz, p);
        p = fmaf(af.w, sw, p);
        // head = 8 consecutive lanes (32 channels); groups aligned to 8
        p += __shfl_xor(p, 1);
        p += __shfl_xor(p, 2);
        p += __shfl_xor(p, 4);
        return p;
    };

    // ---- self-loop (src = dst = i), slot 0 only
    if (slot == 0) {
        float4 v = *(const float4*)(xl + (size_t)i * HC + 4 * q);
        float p = edge_logit(v);
        m = p; l = 1.f; acc = v;
    }

    // ---- incoming edges via CSR, online softmax per slot
    for (int base = 0; base < deg; base += 64) {
        int cnt = min(64, deg - base);
        __syncthreads();
        if (t < cnt) s_src[t] = csr_src[rs + base + t];
        __syncthreads();
        for (int k = slot; k < cnt; k += EPW) {
            int s = s_src[k];
            float4 v = *(const float4*)(xl + (size_t)s * HC + 4 * q);
            float p = edge_logit(v);
            float mn = fmaxf(m, p);
            float sc = __expf(m - mn);
            float w  = __expf(p - mn);
            l = fmaf(l, sc, w);
            acc.x = fmaf(acc.x, sc, w * v.x);
            acc.y = fmaf(acc.y, sc, w * v.y);
            acc.z = fmaf(acc.z, sc, w * v.z);
            acc.w = fmaf(acc.w, sc, w * v.w);
            m = mn;
        }
    }

    // ---- merge edge slots (softmax-state combine)
#pragma unroll
    for (int mask = LPE; mask < 64; mask <<= 1) {
        float mo = __shfl_xor(m, mask);
        float lo = __shfl_xor(l, mask);
        float ax = __shfl_xor(acc.x, mask);
        float ay = __shfl_xor(acc.y, mask);
        float az = __shfl_xor(acc.z, mask);
        float aw = __shfl_xor(acc.w, mask);
        float mm = fmaxf(m, mo);
        float s0 = __expf(m - mm);
        float s1 = __expf(mo - mm);
        l = l * s0 + lo * s1;
        acc.x = acc.x * s0 + ax * s1;
        acc.y = acc.y * s0 + ay * s1;
        acc.z = acc.z * s0 + az * s1;
        acc.w = acc.w * s0 + aw * s1;
        m = mm;
    }

    if (t < LPE) {
        const float4 bi = *(const float4*)(bias + 4 * q);
        float inv = 1.f / (l + 1e-16f);
        float4 o;
        o.x = acc.x * inv + bi.x;
        o.y = acc.y * inv + bi.y;
        o.z = acc.z * inv + bi.z;
        o.w = acc.w * inv + bi.w;
        o.x = (o.x > 0.f) ? o.x : expm1f(o.x);
        o.y = (o.y > 0.f) ? o.y : expm1f(o.y);
        o.z = (o.z > 0.f) ? o.z : expm1f(o.z);
        o.w = (o.w > 0.f) ? o.w : expm1f(o.w);
        *(float4*)(hout + (size_t)i * hstride + 4 * q) = o;
    }
}

// =====================================================================
// Global mean pool (atomics) and MLP head
// =====================================================================
__global__ void pool_kernel(const float* __restrict__ h, int hstride,
                            const int* __restrict__ batch, int N,
                            float* __restrict__ pool, float* __restrict__ pcnt)
{
    int idx = blockIdx.x * blockDim.x + threadIdx.x;
    int n = idx >> 5, c = idx & 31;
    if (n >= N) return;
    int b = batch[n];
    atomicAdd(&pool[(size_t)b * 32 + c], h[(size_t)n * hstride + c]);
    if (c == 0) atomicAdd(&pcnt[b], 1.0f);
}

__global__ void head_kernel(const float* __restrict__ pool, const float* __restrict__ pcnt,
                            const float* __restrict__ meta,
                            const float* __restrict__ Wh1, const float* __restrict__ bh1,
                            const float* __restrict__ Wh2, const float* __restrict__ bh2,
                            float* __restrict__ out)
{
    const int b = blockIdx.x;
    const int t = threadIdx.x;
    __shared__ float z[44];
    if (t < 32)      z[t] = pool[(size_t)b * 32 + t] / fmaxf(pcnt[b], 1.0f);
    else if (t < 44) z[t] = meta[(size_t)b * 12 + (t - 32)];
    __syncthreads();
    float p = 0.f;
    if (t < 32) {
        float hj = bh1[t];
#pragma unroll
        for (int k = 0; k < 44; ++k)
            hj = fmaf(z[k], Wh1[k * 32 + t], hj);
        hj = fmaxf(hj, 0.f);
        p = hj * Wh2[t];
    }
#pragma unroll
    for (int off = 32; off >= 1; off >>= 1)
        p += __shfl_xor(p, off, 64);
    if (t == 0) out[b] = p + bh2[0];
}

// =====================================================================
extern "C" void kernel_launch(void* const* d_in, const int* in_sizes, int n_in,
                              void* d_out, int out_size, void* d_ws, size_t ws_size,
                              hipStream_t stream)
{
    const float* x     = (const float*)d_in[0];
    const int*   ei    = (const int*)d_in[1];
    const int*   batch = (const int*)d_in[2];
    const float* meta  = (const float*)d_in[3];
    const float* Wl[3]  = {(const float*)d_in[4],  (const float*)d_in[10], (const float*)d_in[16]};
    const float* bl[3]  = {(const float*)d_in[5],  (const float*)d_in[11], (const float*)d_in[17]};
    const float* Wr[3]  = {(const float*)d_in[6],  (const float*)d_in[12], (const float*)d_in[18]};
    const float* br[3]  = {(const float*)d_in[7],  (const float*)d_in[13], (const float*)d_in[19]};
    const float* att[3] = {(const float*)d_in[8],  (const float*)d_in[14], (const float*)d_in[20]};
    const float* bb[3]  = {(const float*)d_in[9],  (const float*)d_in[15], (const float*)d_in[21]};
    const float* Wh1 = (const float*)d_in[22];
    const float* bh1 = (const float*)d_in[23];
    const float* Wh2 = (const float*)d_in[24];
    const float* bh2 = (const float*)d_in[25];
    float* out = (float*)d_out;

    const int N  = in_sizes[0] / 128;
    const int E  = in_sizes[1] / 2;
    const int B  = in_sizes[3] / 12;

    char* wsp = (char*)d_ws;
    size_t off_ = 0;
    auto alloc = [&](size_t bytes) {
        char* p = wsp + off_;
        off_ = (off_ + bytes + 255) & ~(size_t)255;
        return p;
    };
    float* xlbuf   = (float*)alloc((size_t)N * 128 * 4);  // xl table (HC <= 128)
    float* xrbuf   = (float*)alloc((size_t)N * 128 * 4);  // xr table
    float* hbuf    = (float*)alloc((size_t)N * 128 * 4);  // layer output (ELU'd)
    int*   cnt     = (int*)alloc((size_t)N * 4);
    int*   rowptr  = (int*)alloc((size_t)(N + 1) * 4);
    int*   cursor  = (int*)alloc((size_t)N * 4);
    int*   csr_src = (int*)alloc((size_t)E * 4);
    float* pool    = (float*)alloc((size_t)B * 32 * 4);
    float* pcnt    = (float*)alloc((size_t)B * 4);

    const int* srcI = ei;
    const int* dstI = ei + E;

    // ---- CSR over dst (real edges; self-loops handled inside gat_fused)
    hipMemsetAsync(cnt, 0, (size_t)N * 4, stream);
    count_kernel<<<(E + 255) / 256, 256, 0, stream>>>(dstI, E, cnt);
    scan_kernel<<<1, 1024, 0, stream>>>(cnt, N, E, rowptr, cursor);
    scatter_kernel<<<(E + 255) / 256, 256, 0, stream>>>(srcI, dstI, E, cursor, csr_src);

    // ---- layer 0 (din=128, H=4, C=32, concat)
    {
        dim3 g((N + 63) / 64, 4);
        gemm_xlxr<64, 64, 32><<<g, 256, 0, stream>>>(x, 128, N, Wl[0], Wr[0], bl[0], br[0], 128, xlbuf, xrbuf);
        gat_fused<4><<<N, 64, 0, stream>>>(xlbuf, xrbuf, rowptr, csr_src, att[0], bb[0], hbuf, 128);
    }
    // ---- layer 1
    {
        dim3 g((N + 63) / 64, 4);
        gemm_xlxr<64, 64, 32><<<g, 256, 0, stream>>>(hbuf, 128, N, Wl[1], Wr[1], bl[1], br[1], 128, xlbuf, xrbuf);
        gat_fused<4><<<N, 64, 0, stream>>>(xlbuf, xrbuf, rowptr, csr_src, att[1], bb[1], hbuf, 128);
    }
    // ---- layer 2 (H=1, concat=False -> mean over 1 head = identity)
    {
        dim3 g((N + 63) / 64, 1);
        gemm_xlxr<64, 64, 32><<<g, 256, 0, stream>>>(hbuf, 128, N, Wl[2], Wr[2], bl[2], br[2], 32, xlbuf, xrbuf);
        gat_fused<1><<<N, 64, 0, stream>>>(xlbuf, xrbuf, rowptr, csr_src, att[2], bb[2], hbuf, 32);
    }
    // ---- global mean pool + head
    hipMemsetAsync(pool, 0, (size_t)B * 32 * 4, stream);
    hipMemsetAsync(pcnt, 0, (size_t)B * 4, stream);
    pool_kernel<<<((N * 32) + 255) / 256, 256, 0, stream>>>(hbuf, 32, batch, N, pool, pcnt);
    head_kernel<<<B, 64, 0, stream>>>(pool, pcnt, meta, Wh1, bh1, Wh2, bh2, out);
}

// Round 4
// 558.096 us; speedup vs baseline: 1.9348x; 1.1919x over previous
//
#include <hip/hip_runtime.h>
#include <cstdint>
#include <cstddef>

#define NEG_SLOPE 0.2f

// =====================================================================
// GEMM: [XL | XR][M x dout each] = A[M x 128] @ [Wl | Wr] + [bl | br]
// BM=64, BN=64, BK=32, 256 threads, 4x4 register tile per thread.
// =====================================================================
template<int BM, int BN, int BK>
__global__ __launch_bounds__(256) void gemm_xlxr(
    const float* __restrict__ A, int lda, int M,
    const float* __restrict__ Wl, const float* __restrict__ Wr,
    const float* __restrict__ bl, const float* __restrict__ br,
    int dout, float* __restrict__ XL, float* __restrict__ XR)
{
    constexpr int PAD = 4;
    __shared__ float As[BK * (BM + PAD)];
    __shared__ float Bs[BK * BN];
    const int t = threadIdx.x;
    const int m0 = blockIdx.x * BM;
    const int n0 = blockIdx.y * BN;
    const int tm = (t / 16) * 4;
    const int tn = (t % 16) * 4;
    float acc[4][4] = {};

    for (int k0 = 0; k0 < 128; k0 += BK) {
#pragma unroll
        for (int i = 0; i < (BM * BK) / (256 * 4); ++i) {
            int chunk = t + i * 256;
            int m  = chunk >> 3;
            int kc = (chunk & 7) * 4;
            int row = m0 + m;
            float4 av = make_float4(0.f, 0.f, 0.f, 0.f);
            if (row < M) av = *(const float4*)(A + (size_t)row * lda + k0 + kc);
            As[(kc + 0) * (BM + PAD) + m] = av.x;
            As[(kc + 1) * (BM + PAD) + m] = av.y;
            As[(kc + 2) * (BM + PAD) + m] = av.z;
            As[(kc + 3) * (BM + PAD) + m] = av.w;
        }
#pragma unroll
        for (int i = 0; i < (BK * BN) / (256 * 4); ++i) {
            int chunk = t + i * 256;
            int k  = chunk >> 4;
            int nc = (chunk & 15) * 4;
            int ng = n0 + nc;
            const float* sp = (ng < dout) ? (Wl + (size_t)(k0 + k) * dout + ng)
                                          : (Wr + (size_t)(k0 + k) * dout + (ng - dout));
            *(float4*)(Bs + k * BN + nc) = *(const float4*)sp;
        }
        __syncthreads();
#pragma unroll
        for (int k = 0; k < BK; ++k) {
            float4 a = *(const float4*)(As + k * (BM + PAD) + tm);
            float4 b = *(const float4*)(Bs + k * BN + tn);
            float av[4] = {a.x, a.y, a.z, a.w};
            float bv[4] = {b.x, b.y, b.z, b.w};
#pragma unroll
            for (int ii = 0; ii < 4; ++ii)
#pragma unroll
                for (int jj = 0; jj < 4; ++jj)
                    acc[ii][jj] = fmaf(av[ii], bv[jj], acc[ii][jj]);
        }
        __syncthreads();
    }
#pragma unroll
    for (int ii = 0; ii < 4; ++ii) {
        int row = m0 + tm + ii;
        if (row >= M) continue;
        int col = n0 + tn;                 // 4-col group lies in one half (dout % 4 == 0)
        const float* bp = (col < dout) ? (bl + col) : (br + (col - dout));
        float4 v;
        float* vv = (float*)&v;
#pragma unroll
        for (int jj = 0; jj < 4; ++jj) vv[jj] = acc[ii][jj] + bp[jj];
        float* outp = (col < dout) ? (XL + (size_t)row * dout + col)
                                   : (XR + (size_t)row * dout + (col - dout));
        *(float4*)outp = v;
    }
}

// =====================================================================
// CSR build over dst: count -> 3-phase device scan -> scatter
// =====================================================================
__global__ void count_kernel(const int* __restrict__ dst, int E, int* __restrict__ cnt)
{
    int e = blockIdx.x * blockDim.x + threadIdx.x;
    if (e < E) atomicAdd(&cnt[dst[e]], 1);
}

// Phase A: per-block (2048-element tile) reduction, coalesced
__global__ __launch_bounds__(256) void scan_partial(
    const int* __restrict__ cnt, int N, int* __restrict__ bsum)
{
    __shared__ int red[4];
    const int t = threadIdx.x;
    const int base = blockIdx.x * 2048;
    int s = 0;
#pragma unroll
    for (int i = 0; i < 8; ++i) {
        int idx = base + t + i * 256;
        if (idx < N) s += cnt[idx];
    }
#pragma unroll
    for (int off = 32; off >= 1; off >>= 1) s += __shfl_xor(s, off);
    if ((t & 63) == 0) red[t >> 6] = s;
    __syncthreads();
    if (t == 0) bsum[blockIdx.x] = red[0] + red[1] + red[2] + red[3];
}

// Phase B: exclusive scan of block sums (nb <= 256) + rowptr[N] = E
__global__ __launch_bounds__(256) void scan_bsums(
    int* __restrict__ bsum, int nb, int E, int* __restrict__ rowptr, int N)
{
    __shared__ int sh[256];
    const int t = threadIdx.x;
    int v = (t < nb) ? bsum[t] : 0;
    sh[t] = v;
    __syncthreads();
    for (int off = 1; off < 256; off <<= 1) {
        int u = (t >= off) ? sh[t - off] : 0;
        __syncthreads();
        sh[t] += u;
        __syncthreads();
    }
    if (t < nb) bsum[t] = sh[t] - v;   // exclusive prefix
    if (t == 0) rowptr[N] = E;
}

// Phase C: per-tile exclusive scan, coalesced in/out via LDS
__global__ __launch_bounds__(256) void scan_final(
    const int* __restrict__ cnt, int N, const int* __restrict__ bsum,
    int* __restrict__ rowptr, int* __restrict__ cursor)
{
    __shared__ int sdat[2048];
    __shared__ int tsum[256];
    const int t = threadIdx.x;
    const int base = blockIdx.x * 2048;
#pragma unroll
    for (int i = 0; i < 8; ++i) {
        int idx = base + t + i * 256;
        sdat[t + i * 256] = (idx < N) ? cnt[idx] : 0;
    }
    __syncthreads();
    int vals[8];
    int s = 0;
#pragma unroll
    for (int j = 0; j < 8; ++j) { vals[j] = sdat[t * 8 + j]; s += vals[j]; }
    tsum[t] = s;
    __syncthreads();
    for (int off = 1; off < 256; off <<= 1) {
        int u = (t >= off) ? tsum[t - off] : 0;
        __syncthreads();
        tsum[t] += u;
        __syncthreads();
    }
    int run = bsum[blockIdx.x] + tsum[t] - s;   // exclusive prefix of this chunk
#pragma unroll
    for (int j = 0; j < 8; ++j) { sdat[t * 8 + j] = run; run += vals[j]; }
    __syncthreads();
#pragma unroll
    for (int i = 0; i < 8; ++i) {
        int idx = base + t + i * 256;
        if (idx < N) {
            int v = sdat[t + i * 256];
            rowptr[idx] = v;
            cursor[idx] = v;
        }
    }
}

__global__ void scatter_kernel(const int* __restrict__ src, const int* __restrict__ dst,
                               int E, int* __restrict__ cursor, int* __restrict__ csr_src)
{
    int e = blockIdx.x * blockDim.x + threadIdx.x;
    if (e < E) {
        int p = atomicAdd(&cursor[dst[e]], 1);
        csr_src[p] = src[e];
    }
}

// =====================================================================
// Fused GATv2 edge phase, float4-per-lane:
//   LPE = HC/4 lanes per edge (H=4: 32, H=1: 8); EPW = 64/LPE edge slots
//   per wave. One wave per dst node. Online softmax per slot; slot
//   states merged via softmax-state combine over xor masks LPE..32.
// =====================================================================
template<int H>
__global__ __launch_bounds__(64) void gat_fused(
    const float* __restrict__ xl, const float* __restrict__ xr,
    const int* __restrict__ rowptr, const int* __restrict__ csr_src,
    const float* __restrict__ att, const float* __restrict__ bias,
    float* __restrict__ hout, int hstride)
{
    constexpr int HC  = 32 * H;
    constexpr int LPE = HC / 4;      // lanes per edge
    constexpr int EPW = 64 / LPE;    // edge slots per wave
    __shared__ int s_src[64];
    const int i    = blockIdx.x;
    const int t    = threadIdx.x;
    const int q    = t % LPE;        // lane within edge group
    const int slot = t / LPE;
    const int rs   = rowptr[i];
    const int deg  = rowptr[i + 1] - rs;

    const float4 xri = *(const float4*)(xr + (size_t)i * HC + 4 * q);
    const float4 af  = *(const float4*)(att + 4 * q);

    float m = -3.0e38f, l = 0.f;
    float4 acc = make_float4(0.f, 0.f, 0.f, 0.f);

    auto edge_logit = [&](const float4& v) -> float {
        float sx = v.x + xri.x, sy = v.y + xri.y, sz = v.z + xri.z, sw = v.w + xri.w;
        sx = (sx > 0.f) ? sx : NEG_SLOPE * sx;
        sy = (sy > 0.f) ? sy : NEG_SLOPE * sy;
        sz = (sz > 0.f) ? sz : NEG_SLOPE * sz;
        sw = (sw > 0.f) ? sw : NEG_SLOPE * sw;
        float p = af.x * sx;
        p = fmaf(af.y, sy, p);
        p = fmaf(af.z, sz, p);
        p = fmaf(af.w, sw, p);
        p += __shfl_xor(p, 1);
        p += __shfl_xor(p, 2);
        p += __shfl_xor(p, 4);
        return p;
    };

    // ---- self-loop (src = dst = i), slot 0 only
    if (slot == 0) {
        float4 v = *(const float4*)(xl + (size_t)i * HC + 4 * q);
        float p = edge_logit(v);
        m = p; l = 1.f; acc = v;
    }

    // ---- incoming edges via CSR, online softmax per slot
    for (int base = 0; base < deg; base += 64) {
        int cnt = min(64, deg - base);
        __syncthreads();
        if (t < cnt) s_src[t] = csr_src[rs + base + t];
        __syncthreads();
        for (int k = slot; k < cnt; k += EPW) {
            int s = s_src[k];
            float4 v = *(const float4*)(xl + (size_t)s * HC + 4 * q);
            float p = edge_logit(v);
            float mn = fmaxf(m, p);
            float sc = __expf(m - mn);
            float w  = __expf(p - mn);
            l = fmaf(l, sc, w);
            acc.x = fmaf(acc.x, sc, w * v.x);
            acc.y = fmaf(acc.y, sc, w * v.y);
            acc.z = fmaf(acc.z, sc, w * v.z);
            acc.w = fmaf(acc.w, sc, w * v.w);
            m = mn;
        }
    }

    // ---- merge edge slots (softmax-state combine)
#pragma unroll
    for (int mask = LPE; mask < 64; mask <<= 1) {
        float mo = __shfl_xor(m, mask);
        float lo = __shfl_xor(l, mask);
        float ax = __shfl_xor(acc.x, mask);
        float ay = __shfl_xor(acc.y, mask);
        float az = __shfl_xor(acc.z, mask);
        float aw = __shfl_xor(acc.w, mask);
        float mm = fmaxf(m, mo);
        float s0 = __expf(m - mm);
        float s1 = __expf(mo - mm);
        l = l * s0 + lo * s1;
        acc.x = acc.x * s0 + ax * s1;
        acc.y = acc.y * s0 + ay * s1;
        acc.z = acc.z * s0 + az * s1;
        acc.w = acc.w * s0 + aw * s1;
        m = mm;
    }

    if (t < LPE) {
        const float4 bi = *(const float4*)(bias + 4 * q);
        float inv = 1.f / (l + 1e-16f);
        float4 o;
        o.x = acc.x * inv + bi.x;
        o.y = acc.y * inv + bi.y;
        o.z = acc.z * inv + bi.z;
        o.w = acc.w * inv + bi.w;
        o.x = (o.x > 0.f) ? o.x : expm1f(o.x);
        o.y = (o.y > 0.f) ? o.y : expm1f(o.y);
        o.z = (o.z > 0.f) ? o.z : expm1f(o.z);
        o.w = (o.w > 0.f) ? o.w : expm1f(o.w);
        *(float4*)(hout + (size_t)i * hstride + 4 * q) = o;
    }
}

// =====================================================================
// Global mean pool (atomics) and MLP head
// =====================================================================
__global__ void pool_kernel(const float* __restrict__ h, int hstride,
                            const int* __restrict__ batch, int N,
                            float* __restrict__ pool, float* __restrict__ pcnt)
{
    int idx = blockIdx.x * blockDim.x + threadIdx.x;
    int n = idx >> 5, c = idx & 31;
    if (n >= N) return;
    int b = batch[n];
    atomicAdd(&pool[(size_t)b * 32 + c], h[(size_t)n * hstride + c]);
    if (c == 0) atomicAdd(&pcnt[b], 1.0f);
}

__global__ void head_kernel(const float* __restrict__ pool, const float* __restrict__ pcnt,
                            const float* __restrict__ meta,
                            const float* __restrict__ Wh1, const float* __restrict__ bh1,
                            const float* __restrict__ Wh2, const float* __restrict__ bh2,
                            float* __restrict__ out)
{
    const int b = blockIdx.x;
    const int t = threadIdx.x;
    __shared__ float z[44];
    if (t < 32)      z[t] = pool[(size_t)b * 32 + t] / fmaxf(pcnt[b], 1.0f);
    else if (t < 44) z[t] = meta[(size_t)b * 12 + (t - 32)];
    __syncthreads();
    float p = 0.f;
    if (t < 32) {
        float hj = bh1[t];
#pragma unroll
        for (int k = 0; k < 44; ++k)
            hj = fmaf(z[k], Wh1[k * 32 + t], hj);
        hj = fmaxf(hj, 0.f);
        p = hj * Wh2[t];
    }
#pragma unroll
    for (int off = 32; off >= 1; off >>= 1)
        p += __shfl_xor(p, off, 64);
    if (t == 0) out[b] = p + bh2[0];
}

// =====================================================================
extern "C" void kernel_launch(void* const* d_in, const int* in_sizes, int n_in,
                              void* d_out, int out_size, void* d_ws, size_t ws_size,
                              hipStream_t stream)
{
    const float* x     = (const float*)d_in[0];
    const int*   ei    = (const int*)d_in[1];
    const int*   batch = (const int*)d_in[2];
    const float* meta  = (const float*)d_in[3];
    const float* Wl[3]  = {(const float*)d_in[4],  (const float*)d_in[10], (const float*)d_in[16]};
    const float* bl[3]  = {(const float*)d_in[5],  (const float*)d_in[11], (const float*)d_in[17]};
    const float* Wr[3]  = {(const float*)d_in[6],  (const float*)d_in[12], (const float*)d_in[18]};
    const float* br[3]  = {(const float*)d_in[7],  (const float*)d_in[13], (const float*)d_in[19]};
    const float* att[3] = {(const float*)d_in[8],  (const float*)d_in[14], (const float*)d_in[20]};
    const float* bb[3]  = {(const float*)d_in[9],  (const float*)d_in[15], (const float*)d_in[21]};
    const float* Wh1 = (const float*)d_in[22];
    const float* bh1 = (const float*)d_in[23];
    const float* Wh2 = (const float*)d_in[24];
    const float* bh2 = (const float*)d_in[25];
    float* out = (float*)d_out;

    const int N  = in_sizes[0] / 128;
    const int E  = in_sizes[1] / 2;
    const int B  = in_sizes[3] / 12;
    const int NB = (N + 2047) / 2048;   // scan tiles (<= 256)

    char* wsp = (char*)d_ws;
    size_t off_ = 0;
    auto alloc = [&](size_t bytes) {
        char* p = wsp + off_;
        off_ = (off_ + bytes + 255) & ~(size_t)255;
        return p;
    };
    float* xlbuf   = (float*)alloc((size_t)N * 128 * 4);  // xl table (HC <= 128)
    float* xrbuf   = (float*)alloc((size_t)N * 128 * 4);  // xr table
    float* hbuf    = (float*)alloc((size_t)N * 128 * 4);  // layer output (ELU'd)
    int*   cnt     = (int*)alloc((size_t)N * 4);
    int*   rowptr  = (int*)alloc((size_t)(N + 1) * 4);
    int*   cursor  = (int*)alloc((size_t)N * 4);
    int*   csr_src = (int*)alloc((size_t)E * 4);
    int*   bsum    = (int*)alloc((size_t)256 * 4);
    float* pool    = (float*)alloc((size_t)B * 32 * 4);
    float* pcnt    = (float*)alloc((size_t)B * 4);

    const int* srcI = ei;
    const int* dstI = ei + E;

    // ---- CSR over dst (real edges; self-loops handled inside gat_fused)
    hipMemsetAsync(cnt, 0, (size_t)N * 4, stream);
    count_kernel<<<(E + 255) / 256, 256, 0, stream>>>(dstI, E, cnt);
    scan_partial<<<NB, 256, 0, stream>>>(cnt, N, bsum);
    scan_bsums<<<1, 256, 0, stream>>>(bsum, NB, E, rowptr, N);
    scan_final<<<NB, 256, 0, stream>>>(cnt, N, bsum, rowptr, cursor);
    scatter_kernel<<<(E + 255) / 256, 256, 0, stream>>>(srcI, dstI, E, cursor, csr_src);

    // ---- layer 0 (din=128, H=4, C=32, concat)
    {
        dim3 g((N + 63) / 64, 4);
        gemm_xlxr<64, 64, 32><<<g, 256, 0, stream>>>(x, 128, N, Wl[0], Wr[0], bl[0], br[0], 128, xlbuf, xrbuf);
        gat_fused<4><<<N, 64, 0, stream>>>(xlbuf, xrbuf, rowptr, csr_src, att[0], bb[0], hbuf, 128);
    }
    // ---- layer 1
    {
        dim3 g((N + 63) / 64, 4);
        gemm_xlxr<64, 64, 32><<<g, 256, 0, stream>>>(hbuf, 128, N, Wl[1], Wr[1], bl[1], br[1], 128, xlbuf, xrbuf);
        gat_fused<4><<<N, 64, 0, stream>>>(xlbuf, xrbuf, rowptr, csr_src, att[1], bb[1], hbuf, 128);
    }
    // ---- layer 2 (H=1, concat=False -> mean over 1 head = identity)
    {
        dim3 g((N + 63) / 64, 1);
        gemm_xlxr<64, 64, 32><<<g, 256, 0, stream>>>(hbuf, 128, N, Wl[2], Wr[2], bl[2], br[2], 32, xlbuf, xrbuf);
        gat_fused<1><<<N, 64, 0, stream>>>(xlbuf, xrbuf, rowptr, csr_src, att[2], bb[2], hbuf, 32);
    }
    // ---- global mean pool + head
    hipMemsetAsync(pool, 0, (size_t)B * 32 * 4, stream);
    hipMemsetAsync(pcnt, 0, (size_t)B * 4, stream);
    pool_kernel<<<((N * 32) + 255) / 256, 256, 0, stream>>>(hbuf, 32, batch, N, pool, pcnt);
    head_kernel<<<B, 64, 0, stream>>>(pool, pcnt, meta, Wh1, bh1, Wh2, bh2, out);
}

// Round 5
// 498.485 us; speedup vs baseline: 2.1662x; 1.1196x over previous
//
#include <hip/hip_runtime.h>
#include <cstdint>
#include <cstddef>

#define NEG_SLOPE 0.2f

// =====================================================================
// GEMM: [XL | XR][M x dout each] = A[M x 128] @ [Wl | Wr] + [bl | br]
// BM=64, BN=64, BK=32, 256 threads, 4x4 register tile per thread.
// =====================================================================
template<int BM, int BN, int BK>
__global__ __launch_bounds__(256) void gemm_xlxr(
    const float* __restrict__ A, int lda, int M,
    const float* __restrict__ Wl, const float* __restrict__ Wr,
    const float* __restrict__ bl, const float* __restrict__ br,
    int dout, float* __restrict__ XL, float* __restrict__ XR)
{
    constexpr int PAD = 4;
    __shared__ float As[BK * (BM + PAD)];
    __shared__ float Bs[BK * BN];
    const int t = threadIdx.x;
    const int m0 = blockIdx.x * BM;
    const int n0 = blockIdx.y * BN;
    const int tm = (t / 16) * 4;
    const int tn = (t % 16) * 4;
    float acc[4][4] = {};

    for (int k0 = 0; k0 < 128; k0 += BK) {
#pragma unroll
        for (int i = 0; i < (BM * BK) / (256 * 4); ++i) {
            int chunk = t + i * 256;
            int m  = chunk >> 3;
            int kc = (chunk & 7) * 4;
            int row = m0 + m;
            float4 av = make_float4(0.f, 0.f, 0.f, 0.f);
            if (row < M) av = *(const float4*)(A + (size_t)row * lda + k0 + kc);
            As[(kc + 0) * (BM + PAD) + m] = av.x;
            As[(kc + 1) * (BM + PAD) + m] = av.y;
            As[(kc + 2) * (BM + PAD) + m] = av.z;
            As[(kc + 3) * (BM + PAD) + m] = av.w;
        }
#pragma unroll
        for (int i = 0; i < (BK * BN) / (256 * 4); ++i) {
            int chunk = t + i * 256;
            int k  = chunk >> 4;
            int nc = (chunk & 15) * 4;
            int ng = n0 + nc;
            const float* sp = (ng < dout) ? (Wl + (size_t)(k0 + k) * dout + ng)
                                          : (Wr + (size_t)(k0 + k) * dout + (ng - dout));
            *(float4*)(Bs + k * BN + nc) = *(const float4*)sp;
        }
        __syncthreads();
#pragma unroll
        for (int k = 0; k < BK; ++k) {
            float4 a = *(const float4*)(As + k * (BM + PAD) + tm);
            float4 b = *(const float4*)(Bs + k * BN + tn);
            float av[4] = {a.x, a.y, a.z, a.w};
            float bv[4] = {b.x, b.y, b.z, b.w};
#pragma unroll
            for (int ii = 0; ii < 4; ++ii)
#pragma unroll
                for (int jj = 0; jj < 4; ++jj)
                    acc[ii][jj] = fmaf(av[ii], bv[jj], acc[ii][jj]);
        }
        __syncthreads();
    }
#pragma unroll
    for (int ii = 0; ii < 4; ++ii) {
        int row = m0 + tm + ii;
        if (row >= M) continue;
        int col = n0 + tn;                 // 4-col group lies in one half (dout % 4 == 0)
        const float* bp = (col < dout) ? (bl + col) : (br + (col - dout));
        float4 v;
        float* vv = (float*)&v;
#pragma unroll
        for (int jj = 0; jj < 4; ++jj) vv[jj] = acc[ii][jj] + bp[jj];
        float* outp = (col < dout) ? (XL + (size_t)row * dout + col)
                                   : (XR + (size_t)row * dout + (col - dout));
        *(float4*)outp = v;
    }
}

// =====================================================================
// CSR build over dst: count -> 3-phase device scan -> scatter
// =====================================================================
__global__ void count_kernel(const int* __restrict__ dst, int E, int* __restrict__ cnt)
{
    int e = blockIdx.x * blockDim.x + threadIdx.x;
    if (e < E) atomicAdd(&cnt[dst[e]], 1);
}

// Phase A: per-block (2048-element tile) reduction, coalesced
__global__ __launch_bounds__(256) void scan_partial(
    const int* __restrict__ cnt, int N, int* __restrict__ bsum)
{
    __shared__ int red[4];
    const int t = threadIdx.x;
    const int base = blockIdx.x * 2048;
    int s = 0;
#pragma unroll
    for (int i = 0; i < 8; ++i) {
        int idx = base + t + i * 256;
        if (idx < N) s += cnt[idx];
    }
#pragma unroll
    for (int off = 32; off >= 1; off >>= 1) s += __shfl_xor(s, off);
    if ((t & 63) == 0) red[t >> 6] = s;
    __syncthreads();
    if (t == 0) bsum[blockIdx.x] = red[0] + red[1] + red[2] + red[3];
}

// Phase B: exclusive scan of block sums (nb <= 256) + rowptr[N] = E
__global__ __launch_bounds__(256) void scan_bsums(
    int* __restrict__ bsum, int nb, int E, int* __restrict__ rowptr, int N)
{
    __shared__ int sh[256];
    const int t = threadIdx.x;
    int v = (t < nb) ? bsum[t] : 0;
    sh[t] = v;
    __syncthreads();
    for (int off = 1; off < 256; off <<= 1) {
        int u = (t >= off) ? sh[t - off] : 0;
        __syncthreads();
        sh[t] += u;
        __syncthreads();
    }
    if (t < nb) bsum[t] = sh[t] - v;   // exclusive prefix
    if (t == 0) rowptr[N] = E;
}

// Phase C: per-tile exclusive scan, coalesced in/out via LDS
__global__ __launch_bounds__(256) void scan_final(
    const int* __restrict__ cnt, int N, const int* __restrict__ bsum,
    int* __restrict__ rowptr, int* __restrict__ cursor)
{
    __shared__ int sdat[2048];
    __shared__ int tsum[256];
    const int t = threadIdx.x;
    const int base = blockIdx.x * 2048;
#pragma unroll
    for (int i = 0; i < 8; ++i) {
        int idx = base + t + i * 256;
        sdat[t + i * 256] = (idx < N) ? cnt[idx] : 0;
    }
    __syncthreads();
    int vals[8];
    int s = 0;
#pragma unroll
    for (int j = 0; j < 8; ++j) { vals[j] = sdat[t * 8 + j]; s += vals[j]; }
    tsum[t] = s;
    __syncthreads();
    for (int off = 1; off < 256; off <<= 1) {
        int u = (t >= off) ? tsum[t - off] : 0;
        __syncthreads();
        tsum[t] += u;
        __syncthreads();
    }
    int run = bsum[blockIdx.x] + tsum[t] - s;   // exclusive prefix of this chunk
#pragma unroll
    for (int j = 0; j < 8; ++j) { sdat[t * 8 + j] = run; run += vals[j]; }
    __syncthreads();
#pragma unroll
    for (int i = 0; i < 8; ++i) {
        int idx = base + t + i * 256;
        if (idx < N) {
            int v = sdat[t + i * 256];
            rowptr[idx] = v;
            cursor[idx] = v;
        }
    }
}

__global__ void scatter_kernel(const int* __restrict__ src, const int* __restrict__ dst,
                               int E, int* __restrict__ cursor, int* __restrict__ csr_src)
{
    int e = blockIdx.x * blockDim.x + threadIdx.x;
    if (e < E) {
        int p = atomicAdd(&cursor[dst[e]], 1);
        csr_src[p] = src[e];
    }
}

// =====================================================================
// Fused GATv2 edge phase, float4-per-lane:
//   LPE = HC/4 lanes per edge (H=4: 32, H=1: 8); EPW = 64/LPE edge slots
//   per wave. One wave per dst node. Online softmax per slot; slot
//   states merged via softmax-state combine over xor masks LPE..32.
// =====================================================================
template<int H>
__global__ __launch_bounds__(64) void gat_fused(
    const float* __restrict__ xl, const float* __restrict__ xr,
    const int* __restrict__ rowptr, const int* __restrict__ csr_src,
    const float* __restrict__ att, const float* __restrict__ bias,
    float* __restrict__ hout, int hstride)
{
    constexpr int HC  = 32 * H;
    constexpr int LPE = HC / 4;      // lanes per edge
    constexpr int EPW = 64 / LPE;    // edge slots per wave
    __shared__ int s_src[64];
    const int i    = blockIdx.x;
    const int t    = threadIdx.x;
    const int q    = t % LPE;        // lane within edge group
    const int slot = t / LPE;
    const int rs   = rowptr[i];
    const int deg  = rowptr[i + 1] - rs;

    const float4 xri = *(const float4*)(xr + (size_t)i * HC + 4 * q);
    const float4 af  = *(const float4*)(att + 4 * q);

    float m = -3.0e38f, l = 0.f;
    float4 acc = make_float4(0.f, 0.f, 0.f, 0.f);

    auto edge_logit = [&](const float4& v) -> float {
        float sx = v.x + xri.x, sy = v.y + xri.y, sz = v.z + xri.z, sw = v.w + xri.w;
        sx = (sx > 0.f) ? sx : NEG_SLOPE * sx;
        sy = (sy > 0.f) ? sy : NEG_SLOPE * sy;
        sz = (sz > 0.f) ? sz : NEG_SLOPE * sz;
        sw = (sw > 0.f) ? sw : NEG_SLOPE * sw;
        float p = af.x * sx;
        p = fmaf(af.y, sy, p);
        p = fmaf(af.z, sz, p);
        p = fmaf(af.w, sw, p);
        p += __shfl_xor(p, 1);
        p += __shfl_xor(p, 2);
        p += __shfl_xor(p, 4);
        return p;
    };

    // ---- self-loop (src = dst = i), slot 0 only
    if (slot == 0) {
        float4 v = *(const float4*)(xl + (size_t)i * HC + 4 * q);
        float p = edge_logit(v);
        m = p; l = 1.f; acc = v;
    }

    // ---- incoming edges via CSR, online softmax per slot
    for (int base = 0; base < deg; base += 64) {
        int cnt = min(64, deg - base);
        __syncthreads();
        if (t < cnt) s_src[t] = csr_src[rs + base + t];
        __syncthreads();
        for (int k = slot; k < cnt; k += EPW) {
            int s = s_src[k];
            float4 v = *(const float4*)(xl + (size_t)s * HC + 4 * q);
            float p = edge_logit(v);
            float mn = fmaxf(m, p);
            float sc = __expf(m - mn);
            float w  = __expf(p - mn);
            l = fmaf(l, sc, w);
            acc.x = fmaf(acc.x, sc, w * v.x);
            acc.y = fmaf(acc.y, sc, w * v.y);
            acc.z = fmaf(acc.z, sc, w * v.z);
            acc.w = fmaf(acc.w, sc, w * v.w);
            m = mn;
        }
    }

    // ---- merge edge slots (softmax-state combine)
#pragma unroll
    for (int mask = LPE; mask < 64; mask <<= 1) {
        float mo = __shfl_xor(m, mask);
        float lo = __shfl_xor(l, mask);
        float ax = __shfl_xor(acc.x, mask);
        float ay = __shfl_xor(acc.y, mask);
        float az = __shfl_xor(acc.z, mask);
        float aw = __shfl_xor(acc.w, mask);
        float mm = fmaxf(m, mo);
        float s0 = __expf(m - mm);
        float s1 = __expf(mo - mm);
        l = l * s0 + lo * s1;
        acc.x = acc.x * s0 + ax * s1;
        acc.y = acc.y * s0 + ay * s1;
        acc.z = acc.z * s0 + az * s1;
        acc.w = acc.w * s0 + aw * s1;
        m = mm;
    }

    if (t < LPE) {
        const float4 bi = *(const float4*)(bias + 4 * q);
        float inv = 1.f / (l + 1e-16f);
        float4 o;
        o.x = acc.x * inv + bi.x;
        o.y = acc.y * inv + bi.y;
        o.z = acc.z * inv + bi.z;
        o.w = acc.w * inv + bi.w;
        o.x = (o.x > 0.f) ? o.x : expm1f(o.x);
        o.y = (o.y > 0.f) ? o.y : expm1f(o.y);
        o.z = (o.z > 0.f) ? o.z : expm1f(o.z);
        o.w = (o.w > 0.f) ? o.w : expm1f(o.w);
        *(float4*)(hout + (size_t)i * hstride + 4 * q) = o;
    }
}

// =====================================================================
// Fused mean-pool + MLP head. One block per graph; batch is SORTED so
// graph b's nodes are rows [lower_bound(b), lower_bound(b+1)) — found by
// per-thread binary search, reduced coalescedly with zero atomics.
// =====================================================================
__global__ __launch_bounds__(128) void pool_head_kernel(
    const float* __restrict__ h, int hstride,
    const int* __restrict__ batch, int N,
    const float* __restrict__ meta,
    const float* __restrict__ Wh1, const float* __restrict__ bh1,
    const float* __restrict__ Wh2, const float* __restrict__ bh2,
    float* __restrict__ out)
{
    const int b = blockIdx.x;
    const int t = threadIdx.x;
    __shared__ float s[128];
    __shared__ float z[44];

    // lower_bound(batch, b) and lower_bound(batch, b+1)
    int lo = 0, hi = N;
    while (lo < hi) { int mid = (lo + hi) >> 1; if (batch[mid] < b) lo = mid + 1; else hi = mid; }
    int lo2 = lo, hi2 = N;
    while (lo2 < hi2) { int mid = (lo2 + hi2) >> 1; if (batch[mid] < b + 1) lo2 = mid + 1; else hi2 = mid; }
    const int start = lo, end = lo2;

    const int c = t & 31, r = t >> 5;     // 4 rows x 32 channels in flight
    float acc = 0.f;
    for (int row = start + r; row < end; row += 4)
        acc += h[(size_t)row * hstride + c];
    s[t] = acc;
    __syncthreads();
    if (t < 32) {
        float sum = s[t] + s[t + 32] + s[t + 64] + s[t + 96];
        z[t] = sum / fmaxf((float)(end - start), 1.0f);
    } else if (t < 44) {
        z[t] = meta[(size_t)b * 12 + (t - 32)];
    }
    __syncthreads();
    if (t < 32) {
        float hj = bh1[t];
#pragma unroll
        for (int k = 0; k < 44; ++k)
            hj = fmaf(z[k], Wh1[k * 32 + t], hj);
        hj = fmaxf(hj, 0.f);
        float p = hj * Wh2[t];
#pragma unroll
        for (int off = 16; off >= 1; off >>= 1)
            p += __shfl_xor(p, off, 32);
        if (t == 0) out[b] = p + bh2[0];
    }
}

// =====================================================================
extern "C" void kernel_launch(void* const* d_in, const int* in_sizes, int n_in,
                              void* d_out, int out_size, void* d_ws, size_t ws_size,
                              hipStream_t stream)
{
    const float* x     = (const float*)d_in[0];
    const int*   ei    = (const int*)d_in[1];
    const int*   batch = (const int*)d_in[2];
    const float* meta  = (const float*)d_in[3];
    const float* Wl[3]  = {(const float*)d_in[4],  (const float*)d_in[10], (const float*)d_in[16]};
    const float* bl[3]  = {(const float*)d_in[5],  (const float*)d_in[11], (const float*)d_in[17]};
    const float* Wr[3]  = {(const float*)d_in[6],  (const float*)d_in[12], (const float*)d_in[18]};
    const float* br[3]  = {(const float*)d_in[7],  (const float*)d_in[13], (const float*)d_in[19]};
    const float* att[3] = {(const float*)d_in[8],  (const float*)d_in[14], (const float*)d_in[20]};
    const float* bb[3]  = {(const float*)d_in[9],  (const float*)d_in[15], (const float*)d_in[21]};
    const float* Wh1 = (const float*)d_in[22];
    const float* bh1 = (const float*)d_in[23];
    const float* Wh2 = (const float*)d_in[24];
    const float* bh2 = (const float*)d_in[25];
    float* out = (float*)d_out;

    const int N  = in_sizes[0] / 128;
    const int E  = in_sizes[1] / 2;
    const int B  = in_sizes[3] / 12;
    const int NB = (N + 2047) / 2048;   // scan tiles (<= 256)

    char* wsp = (char*)d_ws;
    size_t off_ = 0;
    auto alloc = [&](size_t bytes) {
        char* p = wsp + off_;
        off_ = (off_ + bytes + 255) & ~(size_t)255;
        return p;
    };
    float* xlbuf   = (float*)alloc((size_t)N * 128 * 4);  // xl table (HC <= 128)
    float* xrbuf   = (float*)alloc((size_t)N * 128 * 4);  // xr table
    float* hbuf    = (float*)alloc((size_t)N * 128 * 4);  // layer output (ELU'd)
    int*   cnt     = (int*)alloc((size_t)N * 4);
    int*   rowptr  = (int*)alloc((size_t)(N + 1) * 4);
    int*   cursor  = (int*)alloc((size_t)N * 4);
    int*   csr_src = (int*)alloc((size_t)E * 4);
    int*   bsum    = (int*)alloc((size_t)256 * 4);

    const int* srcI = ei;
    const int* dstI = ei + E;

    // ---- CSR over dst (real edges; self-loops handled inside gat_fused)
    hipMemsetAsync(cnt, 0, (size_t)N * 4, stream);
    count_kernel<<<(E + 255) / 256, 256, 0, stream>>>(dstI, E, cnt);
    scan_partial<<<NB, 256, 0, stream>>>(cnt, N, bsum);
    scan_bsums<<<1, 256, 0, stream>>>(bsum, NB, E, rowptr, N);
    scan_final<<<NB, 256, 0, stream>>>(cnt, N, bsum, rowptr, cursor);
    scatter_kernel<<<(E + 255) / 256, 256, 0, stream>>>(srcI, dstI, E, cursor, csr_src);

    // ---- layer 0 (din=128, H=4, C=32, concat)
    {
        dim3 g((N + 63) / 64, 4);
        gemm_xlxr<64, 64, 32><<<g, 256, 0, stream>>>(x, 128, N, Wl[0], Wr[0], bl[0], br[0], 128, xlbuf, xrbuf);
        gat_fused<4><<<N, 64, 0, stream>>>(xlbuf, xrbuf, rowptr, csr_src, att[0], bb[0], hbuf, 128);
    }
    // ---- layer 1
    {
        dim3 g((N + 63) / 64, 4);
        gemm_xlxr<64, 64, 32><<<g, 256, 0, stream>>>(hbuf, 128, N, Wl[1], Wr[1], bl[1], br[1], 128, xlbuf, xrbuf);
        gat_fused<4><<<N, 64, 0, stream>>>(xlbuf, xrbuf, rowptr, csr_src, att[1], bb[1], hbuf, 128);
    }
    // ---- layer 2 (H=1, concat=False -> mean over 1 head = identity)
    {
        dim3 g((N + 63) / 64, 1);
        gemm_xlxr<64, 64, 32><<<g, 256, 0, stream>>>(hbuf, 128, N, Wl[2], Wr[2], bl[2], br[2], 32, xlbuf, xrbuf);
        gat_fused<1><<<N, 64, 0, stream>>>(xlbuf, xrbuf, rowptr, csr_src, att[2], bb[2], hbuf, 32);
    }
    // ---- fused global mean pool + head (batch sorted -> binary search, no atomics)
    pool_head_kernel<<<B, 128, 0, stream>>>(hbuf, 32, batch, N, meta, Wh1, bh1, Wh2, bh2, out);
}